// Round 1
// baseline (243.695 us; speedup 1.0000x reference)
//
#include <hip/hip_runtime.h>
#include <math.h>

#define NB 8
#define NCL 64
#define NCH 128
#define NHL 256
#define NWL 256
#define NPIX 4096     // 64*64
#define NLOW 65536    // 256*256

__device__ __forceinline__ float sigmoidf_(float x){ return 1.0f/(1.0f + __expf(-x)); }

__device__ __forceinline__ float wave_sum(float v){
  #pragma unroll
  for(int o=32;o;o>>=1) v += __shfl_down(v, o, 64);
  return v;
}

// block of 256 threads; result valid on all threads
__device__ __forceinline__ float block_sum256(float v){
  __shared__ float sd[4];
  float w = wave_sum(v);
  if((threadIdx.x & 63) == 0) sd[threadIdx.x >> 6] = w;
  __syncthreads();
  return sd[0] + sd[1] + sd[2] + sd[3];
}

// ---------------- Kernel A: upsample weight vector Wv[64] (sum of bilinear weights 64->256, align_corners) ----
__global__ void k_wv(float* __restrict__ Wv){
  int i = threadIdx.x;
  const float U = 63.0f/255.0f;
  float acc = 0.f;
  for(int k=0;k<256;k++){
    float pos = k*U;
    int i0 = (int)pos; if(i0>63) i0=63;
    float f = pos - (float)i0;
    int i1 = i0+1; if(i1>63) i1=63;
    if(i0==i) acc += 1.0f - f;
    if(i1==i) acc += f;
  }
  Wv[i] = acc;
}

// ---------------- Kernel B: per-(b,c) channel sum of x_low ----------------
__global__ __launch_bounds__(256) void k_pool_low(const float* __restrict__ xlow, float* __restrict__ sum_low){
  int bc = blockIdx.x;
  const float4* P = (const float4*)(xlow + (size_t)bc*NLOW);
  float s = 0.f;
  for(int i=threadIdx.x; i<NLOW/4; i+=256){
    float4 v = P[i];
    s += (v.x+v.y)+(v.z+v.w);
  }
  float t = block_sum256(s);
  if(threadIdx.x==0) sum_low[bc] = t;
}

// ---------------- Kernel C: bilinear downsample x_low 256->64 + sumsq ----------------
__global__ __launch_bounds__(256) void k_down(const float* __restrict__ xlow, float* __restrict__ xl, float* __restrict__ ssql){
  int bc = blockIdx.x;
  const float* X = xlow + (size_t)bc*NLOW;
  const float D = 255.0f/63.0f;
  float ss = 0.f;
  for(int t=threadIdx.x; t<NPIX; t+=256){
    int i = t>>6, j = t&63;
    float ph = i*D; int h0 = (int)ph; if(h0>255) h0=255; float fh = ph - (float)h0; int h1 = h0+1; if(h1>255) h1=255;
    float pw = j*D; int w0 = (int)pw; if(w0>255) w0=255; float fw = pw - (float)w0; int w1 = w0+1; if(w1>255) w1=255;
    const float* r0 = X + h0*256; const float* r1 = X + h1*256;
    float v = (1.f-fh)*((1.f-fw)*r0[w0] + fw*r0[w1]) + fh*((1.f-fw)*r1[w0] + fw*r1[w1]);
    xl[(size_t)bc*NPIX + t] = v;
    ss += v*v;
  }
  float t2 = block_sum256(ss);
  if(threadIdx.x==0) ssql[bc] = t2;
}

// ---------------- Kernel D: per-(b,d) sumsq of x_high ----------------
__global__ __launch_bounds__(256) void k_ssqh(const float* __restrict__ xh, float* __restrict__ ssqh){
  int bd = blockIdx.x;
  const float4* P = (const float4*)(xh + (size_t)bd*NPIX);
  float s = 0.f;
  for(int i=threadIdx.x; i<NPIX/4; i+=256){
    float4 v = P[i];
    s += v.x*v.x + v.y*v.y + v.z*v.z + v.w*v.w;
  }
  float t = block_sum256(s);
  if(threadIdx.x==0) ssqh[bd] = t;
}

// ---------------- Kernel E: cos partial dots over n-chunks of 64 ----------------
// grid = (B * 64 chunks); partial[b][chk][c][d] = sum_{n in chunk} xl[c,n]*xh[d,n]
__global__ __launch_bounds__(256) void k_cospart(const float* __restrict__ xl,
                                                 const float* __restrict__ xh,
                                                 float* __restrict__ cospart){
  __shared__ float xls[64*65];
  __shared__ float xhs[128*65];
  int b = blockIdx.x >> 6;
  int chk = blockIdx.x & 63;
  int n0 = chk * 64;
  for(int idx = threadIdx.x; idx < 64*64; idx += 256){
    int c = idx >> 6, k = idx & 63;
    xls[c*65 + k] = xl[((size_t)b*64 + c)*NPIX + n0 + k];
  }
  for(int idx = threadIdx.x; idx < 128*64; idx += 256){
    int d = idx >> 6, k = idx & 63;
    xhs[d*65 + k] = xh[((size_t)b*128 + d)*NPIX + n0 + k];
  }
  __syncthreads();
  int ci = threadIdx.x & 15, di = threadIdx.x >> 4;
  int c0 = ci*4, d0 = di*8;
  float acc[4][8];
  #pragma unroll
  for(int i=0;i<4;i++)
    #pragma unroll
    for(int j=0;j<8;j++) acc[i][j] = 0.f;
  for(int k=0;k<64;k++){
    float a0 = xls[(c0+0)*65 + k];
    float a1 = xls[(c0+1)*65 + k];
    float a2 = xls[(c0+2)*65 + k];
    float a3 = xls[(c0+3)*65 + k];
    #pragma unroll
    for(int j=0;j<8;j++){
      float bv = xhs[(d0+j)*65 + k];
      acc[0][j] += a0*bv; acc[1][j] += a1*bv; acc[2][j] += a2*bv; acc[3][j] += a3*bv;
    }
  }
  float* op = cospart + (size_t)(b*64 + chk)*8192;
  #pragma unroll
  for(int i=0;i<4;i++){
    float4 v0 = make_float4(acc[i][0],acc[i][1],acc[i][2],acc[i][3]);
    float4 v1 = make_float4(acc[i][4],acc[i][5],acc[i][6],acc[i][7]);
    float4* dst = (float4*)(op + (c0+i)*128 + d0);
    dst[0] = v0; dst[1] = v1;
  }
}

// ---------------- Kernel E2: reduce partials, normalize, softmax over d -> p[b][c][d] ----------------
__global__ __launch_bounds__(128) void k_softmax(const float* __restrict__ cospart,
    const float* __restrict__ ssql, const float* __restrict__ ssqh, float* __restrict__ p){
  int b = blockIdx.x >> 6, c = blockIdx.x & 63;
  int d = threadIdx.x;
  float s = 0.f;
  for(int chk=0; chk<64; chk++)
    s += cospart[(size_t)(b*64 + chk)*8192 + c*128 + d];
  float nl = sqrtf(ssql[b*64 + c]) + 1e-12f;
  float nh = sqrtf(ssqh[b*128 + d]) + 1e-12f;
  float cosv = s / (nl * nh);
  __shared__ float sm[2], ssum[2];
  float m = cosv;
  #pragma unroll
  for(int o=32;o;o>>=1) m = fmaxf(m, __shfl_xor(m, o, 64));
  if((threadIdx.x & 63) == 0) sm[threadIdx.x >> 6] = m;
  __syncthreads();
  m = fmaxf(sm[0], sm[1]);
  float e = __expf(cosv - m);
  float t = e;
  #pragma unroll
  for(int o=32;o;o>>=1) t += __shfl_xor(t, o, 64);
  if((threadIdx.x & 63) == 0) ssum[threadIdx.x >> 6] = t;
  __syncthreads();
  t = ssum[0] + ssum[1];
  p[(size_t)(b*64 + c)*128 + d] = e / t;
}

// ---------------- Kernel F: fused xhc = P @ xh  and  red64 = relu(bn(red_w @ xh)) ----------------
// grid = (B * 32 n-chunks of 128), 256 threads. P_s[r][k]: rows 0..63 = softmax probs, 64..127 = red_w.
__global__ __launch_bounds__(256) void k_pv(const float* __restrict__ p, const float* __restrict__ red_w,
    const float* __restrict__ xh,
    const float* __restrict__ rg, const float* __restrict__ rb,
    const float* __restrict__ rm, const float* __restrict__ rv,
    float* __restrict__ xhc, float* __restrict__ red64){
  __shared__ float P_s[128*128];  // 64 KB
  int b = blockIdx.x >> 5, chk = blockIdx.x & 31;
  int n0 = chk * 128;
  for(int idx = threadIdx.x; idx < 128*128; idx += 256){
    int k = idx & 127, r = idx >> 7;
    P_s[r*128 + k] = (r < 64) ? p[((size_t)b*64 + r)*128 + k]
                              : red_w[(size_t)(r-64)*128 + k];
  }
  __syncthreads();
  int ni = threadIdx.x & 15, ri = threadIdx.x >> 4;
  int n0t = 8*ni, r0 = 8*ri;
  float acc[8][8];
  #pragma unroll
  for(int i=0;i<8;i++)
    #pragma unroll
    for(int j=0;j<8;j++) acc[i][j] = 0.f;
  const float* xrow = xh + (size_t)b*128*NPIX + n0 + n0t;
  #pragma unroll 2
  for(int k=0;k<128;k++){
    float4 x0 = *(const float4*)(xrow + (size_t)k*NPIX);
    float4 x1 = *(const float4*)(xrow + (size_t)k*NPIX + 4);
    #pragma unroll
    for(int rr=0; rr<8; rr++){
      float pw = P_s[(r0+rr)*128 + k];
      acc[rr][0] += pw*x0.x; acc[rr][1] += pw*x0.y; acc[rr][2] += pw*x0.z; acc[rr][3] += pw*x0.w;
      acc[rr][4] += pw*x1.x; acc[rr][5] += pw*x1.y; acc[rr][6] += pw*x1.z; acc[rr][7] += pw*x1.w;
    }
  }
  #pragma unroll
  for(int rr=0; rr<8; rr++){
    int r = r0 + rr;
    if(r < 64){
      float* dst = xhc + ((size_t)b*64 + r)*NPIX + n0 + n0t;
      *(float4*)dst     = make_float4(acc[rr][0],acc[rr][1],acc[rr][2],acc[rr][3]);
      *(float4*)(dst+4) = make_float4(acc[rr][4],acc[rr][5],acc[rr][6],acc[rr][7]);
    } else {
      int o = r - 64;
      float sc = rg[o] * rsqrtf(rv[o] + 1e-5f);
      float bs = rb[o] - rm[o]*sc;
      float v0 = fmaxf(fmaf(acc[rr][0],sc,bs),0.f), v1 = fmaxf(fmaf(acc[rr][1],sc,bs),0.f);
      float v2 = fmaxf(fmaf(acc[rr][2],sc,bs),0.f), v3 = fmaxf(fmaf(acc[rr][3],sc,bs),0.f);
      float v4 = fmaxf(fmaf(acc[rr][4],sc,bs),0.f), v5 = fmaxf(fmaf(acc[rr][5],sc,bs),0.f);
      float v6 = fmaxf(fmaf(acc[rr][6],sc,bs),0.f), v7 = fmaxf(fmaf(acc[rr][7],sc,bs),0.f);
      float* dst = red64 + ((size_t)b*64 + o)*NPIX + n0 + n0t;
      *(float4*)dst     = make_float4(v0,v1,v2,v3);
      *(float4*)(dst+4) = make_float4(v4,v5,v6,v7);
    }
  }
}

// ---------------- Kernel G: weighted mean of upsampled red via Wv ----------------
__global__ __launch_bounds__(256) void k_redmean(const float* __restrict__ red64, const float* __restrict__ Wv,
                                                 float* __restrict__ redmean){
  __shared__ float wv[64];
  int bo = blockIdx.x;
  if(threadIdx.x < 64) wv[threadIdx.x] = Wv[threadIdx.x];
  __syncthreads();
  const float* R = red64 + (size_t)bo*NPIX;
  float acc = 0.f;
  for(int t=threadIdx.x; t<NPIX; t+=256){
    int i = t>>6, j = t&63;
    acc += wv[i]*wv[j]*R[t];
  }
  float s = block_sum256(acc);
  if(threadIdx.x==0) redmean[bo] = s * (1.0f/65536.0f);
}

// ---------------- Kernel H: channel gate att[b][o] ----------------
__global__ void k_att(const float* __restrict__ sum_low, const float* __restrict__ redmean,
                      const float* __restrict__ cw, const float* __restrict__ cb,
                      const float* __restrict__ g, const float* __restrict__ be,
                      const float* __restrict__ mu, const float* __restrict__ va,
                      float* __restrict__ att){
  int b = blockIdx.x; int o = threadIdx.x;
  __shared__ float pool[128];
  for(int j=threadIdx.x; j<128; j+=64)
    pool[j] = (j < 64) ? sum_low[b*64 + j]*(1.0f/65536.0f) : redmean[b*64 + (j-64)];
  __syncthreads();
  float acc = cb[o];
  for(int j=0;j<128;j++) acc += cw[o*128 + j]*pool[j];
  float sc = g[o]*rsqrtf(va[o] + 1e-5f);
  float v = (acc - mu[o])*sc + be[o];
  att[b*64 + o] = sigmoidf_(v);
}

// ---------------- Kernel I: final fused upsample + sigmoid diffs + relu ----------------
// grid = (B*64) blocks, one per (b,c); writes output channels c and c+64.
__global__ __launch_bounds__(256) void k_final(const float* __restrict__ xlow,
    const float* __restrict__ xhc, const float* __restrict__ red64,
    const float* __restrict__ att, float* __restrict__ out){
  __shared__ float sx[NPIX];
  __shared__ float sr[NPIX];
  int b = blockIdx.x >> 6, c = blockIdx.x & 63;
  {
    const float4* A = (const float4*)(xhc   + ((size_t)b*64 + c)*NPIX);
    const float4* Rr= (const float4*)(red64 + ((size_t)b*64 + c)*NPIX);
    for(int i=threadIdx.x; i<NPIX/4; i+=256){
      ((float4*)sx)[i] = A[i];
      ((float4*)sr)[i] = Rr[i];
    }
  }
  __syncthreads();
  float a = att[b*64 + c];
  const float U = 63.0f/255.0f;
  const float* XL = xlow + ((size_t)b*64 + c)*NLOW;
  float* O1 = out + ((size_t)(b*128) + c)*NLOW;
  float* O2 = out + ((size_t)(b*128) + 64 + c)*NLOW;
  for(int q=threadIdx.x; q<NLOW/4; q+=256){
    int h = q >> 6; int wq = q & 63;
    float ph = h*U; int h0 = (int)ph; if(h0>63) h0=63; float fh = ph - (float)h0; int h1 = h0+1; if(h1>63) h1=63;
    const float* r0x = sx + h0*64; const float* r1x = sx + h1*64;
    const float* r0r = sr + h0*64; const float* r1r = sr + h1*64;
    float4 xv = *(const float4*)(XL + q*4);
    float xvv[4] = {xv.x, xv.y, xv.z, xv.w};
    float o1[4], o2[4];
    #pragma unroll
    for(int i=0;i<4;i++){
      int w = wq*4 + i;
      float pw = w*U; int w0 = (int)pw; if(w0>63) w0=63; float fw = pw - (float)w0; int w1 = w0+1; if(w1>63) w1=63;
      float whi = fh, wlo = 1.f - fh, wri = fw, wle = 1.f - fw;
      float vx = wlo*(wle*r0x[w0] + wri*r0x[w1]) + whi*(wle*r1x[w0] + wri*r1x[w1]);
      float vr = wlo*(wle*r0r[w0] + wri*r0r[w1]) + whi*(wle*r1r[w0] + wri*r1r[w1]);
      float sl = sigmoidf_(xvv[i]);
      o1[i] = fmaxf(sl - sigmoidf_(vx), 0.f);
      o2[i] = fmaxf(sl - sigmoidf_(vr*a), 0.f);
    }
    *(float4*)(O1 + q*4) = make_float4(o1[0],o1[1],o1[2],o1[3]);
    *(float4*)(O2 + q*4) = make_float4(o2[0],o2[1],o2[2],o2[3]);
  }
}

extern "C" void kernel_launch(void* const* d_in, const int* in_sizes, int n_in,
                              void* d_out, int out_size, void* d_ws, size_t ws_size,
                              hipStream_t stream) {
  const float* x_low   = (const float*)d_in[0];
  const float* x_high  = (const float*)d_in[1];
  const float* red_w   = (const float*)d_in[2];
  const float* red_g   = (const float*)d_in[3];
  const float* red_b   = (const float*)d_in[4];
  const float* red_m   = (const float*)d_in[5];
  const float* red_v   = (const float*)d_in[6];
  const float* cconv_w = (const float*)d_in[7];
  const float* cconv_b = (const float*)d_in[8];
  const float* cc_g    = (const float*)d_in[9];
  const float* cc_b    = (const float*)d_in[10];
  const float* cc_m    = (const float*)d_in[11];
  const float* cc_v    = (const float*)d_in[12];
  float* out = (float*)d_out;
  float* ws  = (float*)d_ws;

  float* bufA    = ws;               // xl (B*64*4096), later red64
  float* bufB    = ws + 2097152;     // cospart (B*64chunks*64*128 = 4M), later xhc (2M)
  float* p       = ws + 6291456;     // 65536
  float* sum_low = ws + 6356992;     // 512
  float* ssql    = ws + 6357504;     // 512
  float* ssqh    = ws + 6358016;     // 1024
  float* redmean = ws + 6359040;     // 512
  float* att     = ws + 6359552;     // 512
  float* Wv      = ws + 6360064;     // 64

  hipLaunchKernelGGL(k_wv,       dim3(1),    dim3(64),  0, stream, Wv);
  hipLaunchKernelGGL(k_pool_low, dim3(512),  dim3(256), 0, stream, x_low, sum_low);
  hipLaunchKernelGGL(k_down,     dim3(512),  dim3(256), 0, stream, x_low, bufA, ssql);
  hipLaunchKernelGGL(k_ssqh,     dim3(1024), dim3(256), 0, stream, x_high, ssqh);
  hipLaunchKernelGGL(k_cospart,  dim3(512),  dim3(256), 0, stream, bufA, x_high, bufB);
  hipLaunchKernelGGL(k_softmax,  dim3(512),  dim3(128), 0, stream, bufB, ssql, ssqh, p);
  hipLaunchKernelGGL(k_pv,       dim3(256),  dim3(256), 0, stream, p, red_w, x_high,
                     red_g, red_b, red_m, red_v, bufB, bufA);
  hipLaunchKernelGGL(k_redmean,  dim3(512),  dim3(256), 0, stream, bufA, Wv, redmean);
  hipLaunchKernelGGL(k_att,      dim3(8),    dim3(64),  0, stream, sum_low, redmean,
                     cconv_w, cconv_b, cc_g, cc_b, cc_m, cc_v, att);
  hipLaunchKernelGGL(k_final,    dim3(512),  dim3(256), 0, stream, x_low, bufB, bufA, att, out);
}